// Round 6
// baseline (224.021 us; speedup 1.0000x reference)
//
#include <hip/hip_runtime.h>

typedef _Float16 f16;
typedef _Float16 f16x4 __attribute__((ext_vector_type(4)));
typedef _Float16 f16x8 __attribute__((ext_vector_type(8)));
typedef float f32x4 __attribute__((ext_vector_type(4)));

constexpr int NN = 50000;
constexpr int NE = 800000;
constexpr int MP = 50048;   // 782 * 64 (padded row count)
constexpr int CAP = 64;     // bucket capacity per node (Poisson(16) tail ~1e-18)

// fp32 x [50000][128] -> f16 xh [MP][128], pad rows zeroed
__global__ void conv_x(const float* __restrict__ x, f16* __restrict__ xh) {
  int i = blockIdx.x * 256 + threadIdx.x;  // 8 elements per thread
  if (i >= MP * 128 / 8) return;
  int row = i >> 4;
  f16x8 o;
  if (row < NN) {
    const float4* p = (const float4*)(x + (size_t)i * 8);
    float4 a = p[0], b = p[1];
    o = f16x8{(f16)a.x, (f16)a.y, (f16)a.z, (f16)a.w,
              (f16)b.x, (f16)b.y, (f16)b.z, (f16)b.w};
  } else {
    o = f16x8{0, 0, 0, 0, 0, 0, 0, 0};
  }
  *(f16x8*)(xh + (size_t)i * 8) = o;
}

// all four weight transposes in one launch: W [K][N] fp32 -> Wt [N][K] f16
__global__ void conv_w_all(const float* __restrict__ W1i, const float* __restrict__ W2i,
                           const float* __restrict__ W1f, const float* __restrict__ W2f,
                           f16* __restrict__ w1it, f16* __restrict__ w2it,
                           f16* __restrict__ w1ft, f16* __restrict__ w2ft) {
  int i = blockIdx.x * 256 + threadIdx.x;  // total 393216
  const float* W; f16* Wt; int K, N, idx;
  if (i < 65536)       { W = W1i; Wt = w1it; K = 128; N = 512; idx = i; }
  else if (i < 196608) { W = W2i; Wt = w2it; K = 512; N = 256; idx = i - 65536; }
  else if (i < 327680) { W = W1f; Wt = w1ft; K = 256; N = 512; idx = i - 196608; }
  else                 { W = W2f; Wt = w2ft; K = 512; N = 128; idx = i - 327680; }
  int n = idx / K, k = idx - n * K;
  Wt[idx] = (f16)W[(size_t)k * N + n];
}

// build per-dst buckets: one int atomic per edge
__global__ void scatter_edges(const int* __restrict__ src, const int* __restrict__ dst,
                              int* __restrict__ cnt, int* __restrict__ bucket) {
  int e = blockIdx.x * 256 + threadIdx.x;
  if (e >= NE) return;
  int d = dst[e];
  int slot = atomicAdd(&cnt[d], 1);
  if (slot < CAP) bucket[(size_t)d * CAP + slot] = src[e];
}

// one wave per node. Half-wave row layout: lane = (half = l>>5, chunk = l&31);
// each lane loads 16B, one wave-gather covers TWO h-rows; 8-deep => 16 edges in flight.
// Memory-system-bound at compulsory per-XCD fill traffic (~178MB) — do not touch.
__global__ __launch_bounds__(256) void agg_kernel(const f16* __restrict__ h,
    const int* __restrict__ cnt, const int* __restrict__ bucket,
    f16* __restrict__ hagg) {
  int wid = (blockIdx.x * 256 + threadIdx.x) >> 6;
  int l = threadIdx.x & 63;
  if (wid >= NN) return;
  int deg = cnt[wid];
  if (deg > CAP) deg = CAP;
  int s_all = bucket[(size_t)wid * CAP + l];  // lane l holds slot l
  const int half = l >> 5;
  const int lc = l & 31;
  const f16* hb = h + lc * 8;
  float a[8] = {0.f, 0.f, 0.f, 0.f, 0.f, 0.f, 0.f, 0.f};
  int e = 0;
  for (; e + 16 <= deg; e += 16) {
    f16x8 v[8];
    #pragma unroll
    for (int u = 0; u < 8; ++u) {
      int s = __shfl(s_all, e + 2 * u + half);
      v[u] = *(const f16x8*)(hb + (size_t)s * 256);
    }
    #pragma unroll
    for (int u = 0; u < 8; ++u)
      #pragma unroll
      for (int j = 0; j < 8; ++j)
        a[j] += (float)v[u][j];
  }
  for (; e + 2 <= deg; e += 2) {
    int s = __shfl(s_all, e + half);
    f16x8 v = *(const f16x8*)(hb + (size_t)s * 256);
    #pragma unroll
    for (int j = 0; j < 8; ++j) a[j] += (float)v[j];
  }
  if (e < deg) {  // odd leftover: only half 0 contributes
    int s = __shfl(s_all, e);
    if (half == 0) {
      f16x8 v = *(const f16x8*)(hb + (size_t)s * 256);
      #pragma unroll
      for (int j = 0; j < 8; ++j) a[j] += (float)v[j];
    }
  }
  #pragma unroll
  for (int j = 0; j < 8; ++j) a[j] += __shfl_xor(a[j], 32);
  if (half == 0) {
    f16x8 o;
    #pragma unroll
    for (int j = 0; j < 8; ++j) o[j] = (f16)a[j];
    *(f16x8*)(hagg + (size_t)wid * 256 + lc * 8) = o;
  }
}

// C[M][N] = act(A[M][K] @ Wt[N][K]^T + bias). BMx128 tile, BK=64, 4 waves.
// Double-buffered 2-phase: STAGE(next) issued BEFORE compute(cur), ONE barrier
// per K-step (T3 minimum-2-phase recipe). global_load_lds with XOR-swizzled
// global source + matching XOR on ds_read_b128 fragments.
template<int K, int N, int BM, bool RELU, bool OUT_F32>
__global__ __launch_bounds__(256, 2) void gemm_kernel(
    const f16* __restrict__ A, const f16* __restrict__ Wt,
    const float* __restrict__ bias, void* __restrict__ Cout, int Mvalid) {
  constexpr int WM = BM / 2;    // wave tile rows (64 or 32)
  constexpr int MI = WM / 16;   // A fragments per wave (4 or 2)
  constexpr int AIT = BM / 32;  // A staging instructions (4 or 2)
  constexpr int NT = K / 64;    // K-steps
  __shared__ f16 As[2 * BM * 64];
  __shared__ f16 Bs[2 * 128 * 64];
  const int m0 = blockIdx.x * BM;
  const int n0 = blockIdx.y * 128;
  const int t = threadIdx.x;
  const int w = t >> 6, l = t & 63;
  const int wm = (w >> 1) * WM, wn = (w & 1) * 64;
  const int lg = l >> 4, lr = l & 15;
  // staging: per instr, 32 rows x 8 chunks of 16B; physical chunk pc holds
  // logical chunk pc ^ (row & 7)
  const int rs = t >> 3, pc = t & 7;
  f32x4 acc[MI][4] = {};

  auto stage = [&](int buf, int kt) {
    f16* Ab = As + buf * (BM * 64);
    f16* Bb = Bs + buf * (128 * 64);
    #pragma unroll
    for (int it = 0; it < AIT; ++it) {
      int r = it * 32 + rs;
      int lc = pc ^ (r & 7);
      __builtin_amdgcn_global_load_lds(
          (const __attribute__((address_space(1))) void*)(A + (size_t)(m0 + r) * K + kt + lc * 8),
          (__attribute__((address_space(3))) void*)(Ab + (it * 256 + t) * 8), 16, 0, 0);
    }
    #pragma unroll
    for (int it = 0; it < 4; ++it) {
      int r = it * 32 + rs;
      int lc = pc ^ (r & 7);
      __builtin_amdgcn_global_load_lds(
          (const __attribute__((address_space(1))) void*)(Wt + (size_t)(n0 + r) * K + kt + lc * 8),
          (__attribute__((address_space(3))) void*)(Bb + (it * 256 + t) * 8), 16, 0, 0);
    }
  };

  auto compute = [&](int buf) {
    const f16* Ab = As + buf * (BM * 64);
    const f16* Bb = Bs + buf * (128 * 64);
    #pragma unroll
    for (int kk = 0; kk < 64; kk += 32) {
      const int c = (kk >> 3) + lg;  // logical chunk: slot j of group lg <-> k = kk + lg*8 + j
      f16x8 af[MI], bf[4];
      #pragma unroll
      for (int i = 0; i < MI; ++i) {
        int ra = wm + i * 16 + lr;
        af[i] = *(const f16x8*)&Ab[ra * 64 + ((c ^ (ra & 7)) << 3)];
      }
      #pragma unroll
      for (int j = 0; j < 4; ++j) {
        int rb = wn + j * 16 + lr;
        bf[j] = *(const f16x8*)&Bb[rb * 64 + ((c ^ (rb & 7)) << 3)];
      }
      #pragma unroll
      for (int i = 0; i < MI; ++i)
        #pragma unroll
        for (int j = 0; j < 4; ++j)
          acc[i][j] = __builtin_amdgcn_mfma_f32_16x16x32_f16(af[i], bf[j], acc[i][j], 0, 0, 0);
    }
  };

  stage(0, 0);
  __syncthreads();  // vmcnt(0) drain: buf0 ready
  int cur = 0;
  for (int kt = 1; kt < NT; ++kt) {
    stage(cur ^ 1, kt * 64);   // prefetch next tile; flies during compute(cur)
    compute(cur);
    __syncthreads();           // reads of cur done + prefetch landed
    cur ^= 1;
  }
  compute(cur);

  // epilogue: C/D layout col = lane&15, row = (lane>>4)*4 + reg
  #pragma unroll
  for (int i = 0; i < MI; ++i) {
    #pragma unroll
    for (int j = 0; j < 4; ++j) {
      int n = n0 + wn + j * 16 + lr;
      float bv = bias[n];
      #pragma unroll
      for (int r = 0; r < 4; ++r) {
        int m = m0 + wm + i * 16 + lg * 4 + r;
        float v = acc[i][j][r] + bv;
        if (RELU) v = v > 0.f ? v : 0.f;
        if (OUT_F32) {
          if (m < Mvalid) ((float*)Cout)[(size_t)m * N + n] = v;
        } else {
          ((f16*)Cout)[(size_t)m * N + n] = (f16)v;
        }
      }
    }
  }
}

extern "C" void kernel_launch(void* const* d_in, const int* in_sizes, int n_in,
                              void* d_out, int out_size, void* d_ws, size_t ws_size,
                              hipStream_t stream) {
  const float* x   = (const float*)d_in[0];
  const int*   ei  = (const int*)d_in[1];   // [2][NE]: row0 = src, row1 = dst
  const float* W1i = (const float*)d_in[2];
  const float* b1i = (const float*)d_in[3];
  const float* W2i = (const float*)d_in[4];
  const float* b2i = (const float*)d_in[5];
  const float* W1f = (const float*)d_in[6];
  const float* b1f = (const float*)d_in[7];
  const float* W2f = (const float*)d_in[8];
  const float* b2f = (const float*)d_in[9];
  float* out = (float*)d_out;

  char* ws = (char*)d_ws;
  size_t off = 0;
  auto alloc = [&](size_t bytes) -> void* {
    void* p = ws + off;
    off += (bytes + 255) & ~(size_t)255;
    return p;
  };
  f16* xh    = (f16*)alloc((size_t)MP * 128 * 2);
  f16* w1it  = (f16*)alloc((size_t)512 * 128 * 2);
  f16* w2it  = (f16*)alloc((size_t)256 * 512 * 2);
  f16* w1ft  = (f16*)alloc((size_t)512 * 256 * 2);
  f16* w2ft  = (f16*)alloc((size_t)128 * 512 * 2);
  f16* hid   = (f16*)alloc((size_t)MP * 512 * 2);  // reused for hidden1 and hidden2
  f16* h     = (f16*)alloc((size_t)MP * 256 * 2);
  f16* hagg  = (f16*)alloc((size_t)MP * 256 * 2);
  int* cnt   = (int*)alloc((size_t)NN * 4);
  int* bucket= (int*)alloc((size_t)NN * CAP * 4);

  hipMemsetAsync(cnt, 0, (size_t)NN * 4, stream);
  conv_x<<<(MP * 128 / 8 + 255) / 256, 256, 0, stream>>>(x, xh);
  conv_w_all<<<393216 / 256, 256, 0, stream>>>(W1i, W2i, W1f, W2f, w1it, w2it, w1ft, w2ft);
  scatter_edges<<<(NE + 255) / 256, 256, 0, stream>>>(ei, ei + NE, cnt, bucket);

  gemm_kernel<128, 512, 128, true,  false><<<dim3(MP / 128, 4), 256, 0, stream>>>(xh,   w1it, b1i, hid, MP);
  gemm_kernel<512, 256, 128, false, false><<<dim3(MP / 128, 2), 256, 0, stream>>>(hid,  w2it, b2i, h,   MP);
  agg_kernel<<<(NN * 64) / 256, 256, 0, stream>>>(h, cnt, bucket, hagg);
  gemm_kernel<256, 512, 128, true,  false><<<dim3(MP / 128, 4), 256, 0, stream>>>(hagg, w1ft, b1f, hid, MP);
  gemm_kernel<512, 128, 64,  false, true ><<<dim3(MP / 64, 1),  256, 0, stream>>>(hid,  w2ft, b2f, out, NN);
}

// Round 7
// 212.930 us; speedup vs baseline: 1.0521x; 1.0521x over previous
//
#include <hip/hip_runtime.h>

typedef _Float16 f16;
typedef _Float16 f16x4 __attribute__((ext_vector_type(4)));
typedef _Float16 f16x8 __attribute__((ext_vector_type(8)));
typedef float f32x4 __attribute__((ext_vector_type(4)));

constexpr int NN = 50000;
constexpr int NE = 800000;
constexpr int MP = 50048;   // 782 * 64 (padded row count)
constexpr int CAP = 64;     // bucket capacity per node (Poisson(16) tail ~1e-18)

// fp32 x [50000][128] -> f16 xh [MP][128], pad rows zeroed
__global__ void conv_x(const float* __restrict__ x, f16* __restrict__ xh) {
  int i = blockIdx.x * 256 + threadIdx.x;  // 8 elements per thread
  if (i >= MP * 128 / 8) return;
  int row = i >> 4;
  f16x8 o;
  if (row < NN) {
    const float4* p = (const float4*)(x + (size_t)i * 8);
    float4 a = p[0], b = p[1];
    o = f16x8{(f16)a.x, (f16)a.y, (f16)a.z, (f16)a.w,
              (f16)b.x, (f16)b.y, (f16)b.z, (f16)b.w};
  } else {
    o = f16x8{0, 0, 0, 0, 0, 0, 0, 0};
  }
  *(f16x8*)(xh + (size_t)i * 8) = o;
}

// all four weight transposes in one launch: W [K][N] fp32 -> Wt [N][K] f16
__global__ void conv_w_all(const float* __restrict__ W1i, const float* __restrict__ W2i,
                           const float* __restrict__ W1f, const float* __restrict__ W2f,
                           f16* __restrict__ w1it, f16* __restrict__ w2it,
                           f16* __restrict__ w1ft, f16* __restrict__ w2ft) {
  int i = blockIdx.x * 256 + threadIdx.x;  // total 393216
  const float* W; f16* Wt; int K, N, idx;
  if (i < 65536)       { W = W1i; Wt = w1it; K = 128; N = 512; idx = i; }
  else if (i < 196608) { W = W2i; Wt = w2it; K = 512; N = 256; idx = i - 65536; }
  else if (i < 327680) { W = W1f; Wt = w1ft; K = 256; N = 512; idx = i - 196608; }
  else                 { W = W2f; Wt = w2ft; K = 512; N = 128; idx = i - 327680; }
  int n = idx / K, k = idx - n * K;
  Wt[idx] = (f16)W[(size_t)k * N + n];
}

// build per-dst buckets: one int atomic per edge
__global__ void scatter_edges(const int* __restrict__ src, const int* __restrict__ dst,
                              int* __restrict__ cnt, int* __restrict__ bucket) {
  int e = blockIdx.x * 256 + threadIdx.x;
  if (e >= NE) return;
  int d = dst[e];
  int slot = atomicAdd(&cnt[d], 1);
  if (slot < CAP) bucket[(size_t)d * CAP + slot] = src[e];
}

// one wave per node. Half-wave rows: lane = (half = l>>5, chunk = l&31), 16B/lane,
// one wave-gather covers TWO h-rows. deg processed in up-to-4 FULLY-ISSUED batches
// of 16 edges with masked-FMA accumulation — no serial remainder loop (bucket is
// pre-zeroed so slots >= deg load valid row 0 and get masked to zero).
__global__ __launch_bounds__(256) void agg_kernel(const f16* __restrict__ h,
    const int* __restrict__ cnt, const int* __restrict__ bucket,
    f16* __restrict__ hagg) {
  int wid = (blockIdx.x * 256 + threadIdx.x) >> 6;
  int l = threadIdx.x & 63;
  if (wid >= NN) return;
  int deg = cnt[wid];
  if (deg > CAP) deg = CAP;
  int s_all = bucket[(size_t)wid * CAP + l];  // lane l holds slot l (always valid)
  const int half = l >> 5;
  const int lc = l & 31;
  const f16* hb = h + lc * 8;
  float a[8] = {0.f, 0.f, 0.f, 0.f, 0.f, 0.f, 0.f, 0.f};
  for (int base = 0; base < CAP; base += 16) {
    if (base >= deg) break;
    f16x8 v[8];
    #pragma unroll
    for (int u = 0; u < 8; ++u) {
      int s = __shfl(s_all, base + 2 * u + half);
      v[u] = *(const f16x8*)(hb + (size_t)s * 256);
    }
    #pragma unroll
    for (int u = 0; u < 8; ++u) {
      float m = (base + 2 * u + half < deg) ? 1.f : 0.f;
      #pragma unroll
      for (int j = 0; j < 8; ++j)
        a[j] = fmaf(m, (float)v[u][j], a[j]);
    }
  }
  #pragma unroll
  for (int j = 0; j < 8; ++j) a[j] += __shfl_xor(a[j], 32);
  if (half == 0) {
    f16x8 o;
    #pragma unroll
    for (int j = 0; j < 8; ++j) o[j] = (f16)a[j];
    *(f16x8*)(hagg + (size_t)wid * 256 + lc * 8) = o;
  }
}

// C[M][N] = act(A[M][K] @ Wt[N][K]^T + bias). BMx128 tile, BK=64, 4 waves.
// SINGLE-buffered (round-5 structure): 32KB LDS -> ~5 blocks/CU; implicit
// inter-block overlap (m114) beats explicit dbuf at 2 blocks/CU (round-6 regression).
// global_load_lds staging (linear LDS dest) + XOR-swizzled global SOURCE;
// fragment reads = single ds_read_b128 with matching XOR (k-permutation freedom).
template<int K, int N, int BM, bool RELU, bool OUT_F32>
__global__ __launch_bounds__(256, 2) void gemm_kernel(
    const f16* __restrict__ A, const f16* __restrict__ Wt,
    const float* __restrict__ bias, void* __restrict__ Cout, int Mvalid) {
  constexpr int WM = BM / 2;    // wave tile rows (64 or 32)
  constexpr int MI = WM / 16;   // A fragments per wave (4 or 2)
  constexpr int AIT = BM / 32;  // A staging instructions (4 or 2)
  __shared__ f16 As[BM * 64];
  __shared__ f16 Bs[128 * 64];
  const int m0 = blockIdx.x * BM;
  const int n0 = blockIdx.y * 128;
  const int t = threadIdx.x;
  const int w = t >> 6, l = t & 63;
  const int wm = (w >> 1) * WM, wn = (w & 1) * 64;
  const int lg = l >> 4, lr = l & 15;
  // staging: per instr, 32 rows x 8 chunks of 16B; physical chunk pc holds
  // logical chunk pc ^ (row & 7)
  const int rs = t >> 3, pc = t & 7;
  f32x4 acc[MI][4] = {};
  for (int kt = 0; kt < K; kt += 64) {
    #pragma unroll
    for (int it = 0; it < AIT; ++it) {
      int r = it * 32 + rs;
      int lc = pc ^ (r & 7);
      __builtin_amdgcn_global_load_lds(
          (const __attribute__((address_space(1))) void*)(A + (size_t)(m0 + r) * K + kt + lc * 8),
          (__attribute__((address_space(3))) void*)(As + (it * 256 + t) * 8), 16, 0, 0);
    }
    #pragma unroll
    for (int it = 0; it < 4; ++it) {
      int r = it * 32 + rs;
      int lc = pc ^ (r & 7);
      __builtin_amdgcn_global_load_lds(
          (const __attribute__((address_space(1))) void*)(Wt + (size_t)(n0 + r) * K + kt + lc * 8),
          (__attribute__((address_space(3))) void*)(Bs + (it * 256 + t) * 8), 16, 0, 0);
    }
    __syncthreads();  // drains vmcnt before barrier
    #pragma unroll
    for (int kk = 0; kk < 64; kk += 32) {
      const int c = (kk >> 3) + lg;  // logical chunk: slot j of group lg <-> k = kk + lg*8 + j
      f16x8 af[MI], bf[4];
      #pragma unroll
      for (int i = 0; i < MI; ++i) {
        int ra = wm + i * 16 + lr;
        af[i] = *(const f16x8*)&As[ra * 64 + ((c ^ (ra & 7)) << 3)];
      }
      #pragma unroll
      for (int j = 0; j < 4; ++j) {
        int rb = wn + j * 16 + lr;
        bf[j] = *(const f16x8*)&Bs[rb * 64 + ((c ^ (rb & 7)) << 3)];
      }
      #pragma unroll
      for (int i = 0; i < MI; ++i)
        #pragma unroll
        for (int j = 0; j < 4; ++j)
          acc[i][j] = __builtin_amdgcn_mfma_f32_16x16x32_f16(af[i], bf[j], acc[i][j], 0, 0, 0);
    }
    __syncthreads();
  }
  // epilogue: C/D layout col = lane&15, row = (lane>>4)*4 + reg
  #pragma unroll
  for (int i = 0; i < MI; ++i) {
    #pragma unroll
    for (int j = 0; j < 4; ++j) {
      int n = n0 + wn + j * 16 + lr;
      float bv = bias[n];
      #pragma unroll
      for (int r = 0; r < 4; ++r) {
        int m = m0 + wm + i * 16 + lg * 4 + r;
        float v = acc[i][j][r] + bv;
        if (RELU) v = v > 0.f ? v : 0.f;
        if (OUT_F32) {
          if (m < Mvalid) ((float*)Cout)[(size_t)m * N + n] = v;
        } else {
          ((f16*)Cout)[(size_t)m * N + n] = (f16)v;
        }
      }
    }
  }
}

extern "C" void kernel_launch(void* const* d_in, const int* in_sizes, int n_in,
                              void* d_out, int out_size, void* d_ws, size_t ws_size,
                              hipStream_t stream) {
  const float* x   = (const float*)d_in[0];
  const int*   ei  = (const int*)d_in[1];   // [2][NE]: row0 = src, row1 = dst
  const float* W1i = (const float*)d_in[2];
  const float* b1i = (const float*)d_in[3];
  const float* W2i = (const float*)d_in[4];
  const float* b2i = (const float*)d_in[5];
  const float* W1f = (const float*)d_in[6];
  const float* b1f = (const float*)d_in[7];
  const float* W2f = (const float*)d_in[8];
  const float* b2f = (const float*)d_in[9];
  float* out = (float*)d_out;

  char* ws = (char*)d_ws;
  size_t off = 0;
  auto alloc = [&](size_t bytes) -> void* {
    void* p = ws + off;
    off += (bytes + 255) & ~(size_t)255;
    return p;
  };
  f16* xh    = (f16*)alloc((size_t)MP * 128 * 2);
  f16* w1it  = (f16*)alloc((size_t)512 * 128 * 2);
  f16* w2it  = (f16*)alloc((size_t)256 * 512 * 2);
  f16* w1ft  = (f16*)alloc((size_t)512 * 256 * 2);
  f16* w2ft  = (f16*)alloc((size_t)128 * 512 * 2);
  f16* hid   = (f16*)alloc((size_t)MP * 512 * 2);  // reused for hidden1 and hidden2
  f16* h     = (f16*)alloc((size_t)MP * 256 * 2);
  f16* hagg  = (f16*)alloc((size_t)MP * 256 * 2);
  int* cnt   = (int*)alloc((size_t)NN * 4);
  int* bucket= (int*)alloc((size_t)NN * CAP * 4);

  hipMemsetAsync(cnt, 0, (size_t)NN * 4, stream);
  hipMemsetAsync(bucket, 0, (size_t)NN * CAP * 4, stream);  // slots >= deg -> row 0 (masked)
  conv_x<<<(MP * 128 / 8 + 255) / 256, 256, 0, stream>>>(x, xh);
  conv_w_all<<<393216 / 256, 256, 0, stream>>>(W1i, W2i, W1f, W2f, w1it, w2it, w1ft, w2ft);
  scatter_edges<<<(NE + 255) / 256, 256, 0, stream>>>(ei, ei + NE, cnt, bucket);

  gemm_kernel<128, 512, 128, true,  false><<<dim3(MP / 128, 4), 256, 0, stream>>>(xh,   w1it, b1i, hid, MP);
  gemm_kernel<512, 256, 128, false, false><<<dim3(MP / 128, 2), 256, 0, stream>>>(hid,  w2it, b2i, h,   MP);
  agg_kernel<<<(NN * 64) / 256, 256, 0, stream>>>(h, cnt, bucket, hagg);
  gemm_kernel<256, 512, 128, true,  false><<<dim3(MP / 128, 4), 256, 0, stream>>>(hagg, w1ft, b1f, hid, MP);
  gemm_kernel<512, 128, 64,  false, true ><<<dim3(MP / 64, 1),  256, 0, stream>>>(hid,  w2ft, b2f, out, NN);
}

// Round 8
// 190.976 us; speedup vs baseline: 1.1730x; 1.1150x over previous
//
#include <hip/hip_runtime.h>

typedef _Float16 f16;
typedef _Float16 f16x4 __attribute__((ext_vector_type(4)));
typedef _Float16 f16x8 __attribute__((ext_vector_type(8)));
typedef float f32x4 __attribute__((ext_vector_type(4)));

constexpr int NN = 50000;
constexpr int NE = 800000;
constexpr int MP = 50048;   // 782 * 64 (padded row count)
constexpr int CAP = 64;     // bucket capacity per node (Poisson(16) tail ~1e-18)

// all four weight transposes in one launch: W [K][N] fp32 -> Wt [N][K] f16
__global__ void conv_w_all(const float* __restrict__ W1i, const float* __restrict__ W2i,
                           const float* __restrict__ W1f, const float* __restrict__ W2f,
                           f16* __restrict__ w1it, f16* __restrict__ w2it,
                           f16* __restrict__ w1ft, f16* __restrict__ w2ft) {
  int i = blockIdx.x * 256 + threadIdx.x;  // total 393216
  const float* W; f16* Wt; int K, N, idx;
  if (i < 65536)       { W = W1i; Wt = w1it; K = 128; N = 512; idx = i; }
  else if (i < 196608) { W = W2i; Wt = w2it; K = 512; N = 256; idx = i - 65536; }
  else if (i < 327680) { W = W1f; Wt = w1ft; K = 256; N = 512; idx = i - 196608; }
  else                 { W = W2f; Wt = w2ft; K = 512; N = 128; idx = i - 327680; }
  int n = idx / K, k = idx - n * K;
  Wt[idx] = (f16)W[(size_t)k * N + n];
}

// build per-dst buckets: one int atomic per edge
__global__ void scatter_edges(const int* __restrict__ src, const int* __restrict__ dst,
                              int* __restrict__ cnt, int* __restrict__ bucket) {
  int e = blockIdx.x * 256 + threadIdx.x;
  if (e >= NE) return;
  int d = dst[e];
  int slot = atomicAdd(&cnt[d], 1);
  if (slot < CAP) bucket[(size_t)d * CAP + slot] = src[e];
}

// one wave per node. Half-wave rows: 16B/lane, one wave-gather covers TWO h-rows.
// Fully-batched masked-FMA accumulation; unwritten slots (garbage) are clamped to
// row 0 and masked to zero. BANDWIDTH-BOUND at compulsory per-XCD fill (~178MB,
// ~3.2 TB/s fill path) — three structural variants all land at ~55.5us; do not touch.
__global__ __launch_bounds__(256) void agg_kernel(const f16* __restrict__ h,
    const int* __restrict__ cnt, const int* __restrict__ bucket,
    f16* __restrict__ hagg) {
  int wid = (blockIdx.x * 256 + threadIdx.x) >> 6;
  int l = threadIdx.x & 63;
  if (wid >= NN) return;
  int deg = cnt[wid];
  if (deg > CAP) deg = CAP;
  int s_all = bucket[(size_t)wid * CAP + l];  // lane l holds slot l (may be garbage if l >= deg)
  const int half = l >> 5;
  const int lc = l & 31;
  const f16* hb = h + lc * 8;
  float a[8] = {0.f, 0.f, 0.f, 0.f, 0.f, 0.f, 0.f, 0.f};
  for (int base = 0; base < CAP; base += 16) {
    if (base >= deg) break;
    f16x8 v[8];
    #pragma unroll
    for (int u = 0; u < 8; ++u) {
      int s = __shfl(s_all, base + 2 * u + half);
      s = ((unsigned)s < (unsigned)NN) ? s : 0;  // clamp garbage slots (masked below)
      v[u] = *(const f16x8*)(hb + (size_t)s * 256);
    }
    #pragma unroll
    for (int u = 0; u < 8; ++u) {
      float m = (base + 2 * u + half < deg) ? 1.f : 0.f;
      #pragma unroll
      for (int j = 0; j < 8; ++j)
        a[j] = fmaf(m, (float)v[u][j], a[j]);
    }
  }
  #pragma unroll
  for (int j = 0; j < 8; ++j) a[j] += __shfl_xor(a[j], 32);
  if (half == 0) {
    f16x8 o;
    #pragma unroll
    for (int j = 0; j < 8; ++j) o[j] = (f16)a[j];
    *(f16x8*)(hagg + (size_t)wid * 256 + lc * 8) = o;
  }
}

// C[M][N] = act(A @ Wt^T + bias). BMxBN tile, BK=64, 4 waves (2x2).
// Single-buffered (5-6 blocks/CU; implicit inter-block overlap per m114 beats
// explicit dbuf at low occupancy — round-6 evidence). Small BM=64 tiles so
// grid >= 6 blocks/CU even for N=128/256 GEMMs (round-7: G2/G4 were grid-starved).
// global_load_lds staging + XOR-swizzled global SOURCE; fragment reads =
// ds_read_b128 with matching XOR (k-permutation freedom: A/B share the map).
// A_F32: stage A from fp32 via reg-cvt (fuses the x->f16 conversion into GEMM1).
// 1-D grid, m-major bijective XCD swizzle (m204): same-A-panel blocks -> same XCD L2.
template<int K, int N, int BM, int BN, bool A_F32, bool RELU, bool OUT_F32>
__global__ __launch_bounds__(256, 2) void gemm_kernel(
    const void* __restrict__ Ain, const f16* __restrict__ Wt,
    const float* __restrict__ bias, void* __restrict__ Cout, int Mvalid) {
  constexpr int WM = BM / 2, WN = BN / 2;
  constexpr int MI = WM / 16, NJ = WN / 16;
  constexpr int AIT = BM / 32, BIT = BN / 32;
  constexpr int GY = N / BN;
  __shared__ f16 As[BM * 64];
  __shared__ f16 Bs[BN * 64];
  // bijective XCD swizzle: chunk the m-major linear order across 8 XCDs
  const int nwg = gridDim.x;
  const int orig = blockIdx.x;
  const int xcd = orig & 7, lid = orig >> 3;
  const int q = nwg >> 3, r = nwg & 7;
  const int v = (xcd < r ? xcd * (q + 1) : r * (q + 1) + (xcd - r) * q) + lid;
  const int m0 = (v / GY) * BM;
  const int n0 = (v % GY) * BN;
  const int t = threadIdx.x;
  const int w = t >> 6, l = t & 63;
  const int wm = (w >> 1) * WM, wn = (w & 1) * WN;
  const int lg = l >> 4, lr = l & 15;
  // staging: per instr, 32 rows x 8 chunks of 16B; physical chunk pc holds
  // logical chunk pc ^ (row & 7)
  const int rs = t >> 3, pc = t & 7;
  f32x4 acc[MI][NJ] = {};
  for (int kt = 0; kt < K; kt += 64) {
    #pragma unroll
    for (int it = 0; it < AIT; ++it) {
      int rr = it * 32 + rs;
      int lc = pc ^ (rr & 7);
      if constexpr (A_F32) {
        int rg = m0 + rr; if (rg > NN - 1) rg = NN - 1;  // pad rows: any valid data
        const float4* p = (const float4*)((const float*)Ain + (size_t)rg * K + kt + lc * 8);
        float4 u0 = p[0], u1 = p[1];
        f16x8 o = {(f16)u0.x, (f16)u0.y, (f16)u0.z, (f16)u0.w,
                   (f16)u1.x, (f16)u1.y, (f16)u1.z, (f16)u1.w};
        *(f16x8*)(As + (it * 256 + t) * 8) = o;
      } else {
        __builtin_amdgcn_global_load_lds(
            (const __attribute__((address_space(1))) void*)((const f16*)Ain + (size_t)(m0 + rr) * K + kt + lc * 8),
            (__attribute__((address_space(3))) void*)(As + (it * 256 + t) * 8), 16, 0, 0);
      }
    }
    #pragma unroll
    for (int it = 0; it < BIT; ++it) {
      int rr = it * 32 + rs;
      int lc = pc ^ (rr & 7);
      __builtin_amdgcn_global_load_lds(
          (const __attribute__((address_space(1))) void*)(Wt + (size_t)(n0 + rr) * K + kt + lc * 8),
          (__attribute__((address_space(3))) void*)(Bs + (it * 256 + t) * 8), 16, 0, 0);
    }
    __syncthreads();  // drains vmcnt+lgkmcnt before barrier
    #pragma unroll
    for (int kk = 0; kk < 64; kk += 32) {
      const int c = (kk >> 3) + lg;  // logical chunk: slot j of group lg <-> k = kk + lg*8 + j
      f16x8 af[MI], bf[NJ];
      #pragma unroll
      for (int i = 0; i < MI; ++i) {
        int ra = wm + i * 16 + lr;
        af[i] = *(const f16x8*)&As[ra * 64 + ((c ^ (ra & 7)) << 3)];
      }
      #pragma unroll
      for (int j = 0; j < NJ; ++j) {
        int rb = wn + j * 16 + lr;
        bf[j] = *(const f16x8*)&Bs[rb * 64 + ((c ^ (rb & 7)) << 3)];
      }
      #pragma unroll
      for (int i = 0; i < MI; ++i)
        #pragma unroll
        for (int j = 0; j < NJ; ++j)
          acc[i][j] = __builtin_amdgcn_mfma_f32_16x16x32_f16(af[i], bf[j], acc[i][j], 0, 0, 0);
    }
    __syncthreads();
  }
  // epilogue: C/D layout col = lane&15, row = (lane>>4)*4 + reg
  #pragma unroll
  for (int i = 0; i < MI; ++i) {
    #pragma unroll
    for (int j = 0; j < NJ; ++j) {
      int n = n0 + wn + j * 16 + lr;
      float bv = bias[n];
      #pragma unroll
      for (int rg = 0; rg < 4; ++rg) {
        int m = m0 + wm + i * 16 + lg * 4 + rg;
        float vv = acc[i][j][rg] + bv;
        if (RELU) vv = vv > 0.f ? vv : 0.f;
        if (OUT_F32) {
          if (m < Mvalid) ((float*)Cout)[(size_t)m * N + n] = vv;
        } else {
          ((f16*)Cout)[(size_t)m * N + n] = (f16)vv;
        }
      }
    }
  }
}

extern "C" void kernel_launch(void* const* d_in, const int* in_sizes, int n_in,
                              void* d_out, int out_size, void* d_ws, size_t ws_size,
                              hipStream_t stream) {
  const float* x   = (const float*)d_in[0];
  const int*   ei  = (const int*)d_in[1];   // [2][NE]: row0 = src, row1 = dst
  const float* W1i = (const float*)d_in[2];
  const float* b1i = (const float*)d_in[3];
  const float* W2i = (const float*)d_in[4];
  const float* b2i = (const float*)d_in[5];
  const float* W1f = (const float*)d_in[6];
  const float* b1f = (const float*)d_in[7];
  const float* W2f = (const float*)d_in[8];
  const float* b2f = (const float*)d_in[9];
  float* out = (float*)d_out;

  char* ws = (char*)d_ws;
  size_t off = 0;
  auto alloc = [&](size_t bytes) -> void* {
    void* p = ws + off;
    off += (bytes + 255) & ~(size_t)255;
    return p;
  };
  f16* w1it  = (f16*)alloc((size_t)512 * 128 * 2);
  f16* w2it  = (f16*)alloc((size_t)256 * 512 * 2);
  f16* w1ft  = (f16*)alloc((size_t)512 * 256 * 2);
  f16* w2ft  = (f16*)alloc((size_t)128 * 512 * 2);
  f16* hid   = (f16*)alloc((size_t)MP * 512 * 2);  // reused for hidden1 and hidden2
  f16* h     = (f16*)alloc((size_t)MP * 256 * 2);
  f16* hagg  = (f16*)alloc((size_t)MP * 256 * 2);
  int* cnt   = (int*)alloc((size_t)NN * 4);
  int* bucket= (int*)alloc((size_t)NN * CAP * 4);

  hipMemsetAsync(cnt, 0, (size_t)NN * 4, stream);
  conv_w_all<<<393216 / 256, 256, 0, stream>>>(W1i, W2i, W1f, W2f, w1it, w2it, w1ft, w2ft);
  scatter_edges<<<(NE + 255) / 256, 256, 0, stream>>>(ei, ei + NE, cnt, bucket);

  // G1: fuses x f32->f16 conversion into A-staging
  gemm_kernel<128, 512, 64, 128, true,  true,  false><<<(MP / 64) * 4, 256, 0, stream>>>(x,    w1it, b1i, hid, MP);
  gemm_kernel<512, 256, 64, 128, false, false, false><<<(MP / 64) * 2, 256, 0, stream>>>(hid,  w2it, b2i, h,   MP);
  agg_kernel<<<(NN * 64) / 256, 256, 0, stream>>>(h, cnt, bucket, hagg);
  gemm_kernel<256, 512, 64, 128, false, true,  false><<<(MP / 64) * 4, 256, 0, stream>>>(hagg, w1ft, b1f, hid, MP);
  gemm_kernel<512, 128, 64, 64,  false, false, true ><<<(MP / 64) * 2, 256, 0, stream>>>(hid,  w2ft, b2f, out, NN);
}